// Round 4
// baseline (3666.961 us; speedup 1.0000x reference)
//
#include <hip/hip_runtime.h>
#include <stdint.h>

#define T_STEPS 512
#define B_ALL   512
#define SDIM    64
#define HID     128
#define ADIM    10
#define CB      32      // batch rows per chunk
#define PSTEP   16u     // cnt1 signals per chunk-step (8 WGs * 2 waves)
#define NSLOT   4       // h buffer depth (anti-deps at t-3)

typedef __attribute__((ext_vector_type(4))) float f32x4;
typedef __attribute__((ext_vector_type(8))) short s16x8;
typedef unsigned long long u64;

#define MFMA(a,b,c) __builtin_amdgcn_mfma_f32_16x16x32_bf16(a,b,c,0,0,0)
#define SC_AGENT __HIP_MEMORY_SCOPE_AGENT
#define TAGM   0x4000000040000000ull    // bit30 of each packed u32 word
#define STRIPM 0xBFFFFFFFBFFFFFFFull

__device__ __forceinline__ unsigned short bf_rne(float f){
    union{float f; unsigned int u;} v; v.f = f;
    unsigned int r = v.u + 0x7fffu + ((v.u >> 16) & 1u);
    return (unsigned short)(r >> 16);
}
__device__ __forceinline__ float us_to_f(unsigned short h){
    union{unsigned int u; float f;} v; v.u = ((unsigned int)h) << 16; return v.f;
}
__device__ __forceinline__ void split_pair(float f, unsigned short& hi, unsigned short& lo){
    hi = bf_rne(f);
    lo = bf_rne(f - us_to_f(hi));
}
// h-store split: |h|<1 mathematically, but bf_rne can round to +-1.0 (exp=127,
// bit30 set -> would corrupt the tag). Clamp hi to +-0x3f7f; lo absorbs the
// residual at full precision (lo <= ~0.004, bf16 rel 2^-9 -> abs err ~2^-17).
__device__ __forceinline__ void split_h(float f, unsigned short& hi, unsigned short& lo){
    unsigned short h0 = bf_rne(f);
    if ((h0 & 0x7fffu) >= 0x3f80u) h0 = (h0 & 0x8000u) | 0x3f7fu;
    hi = h0;
    lo = bf_rne(f - us_to_f(h0));
}
__device__ __forceinline__ void load_split8(const float* p, s16x8& h, s16x8& l){
#pragma unroll
    for (int i = 0; i < 8; i++){
        unsigned short a, b; split_pair(p[i], a, b);
        h[i] = (short)a; l[i] = (short)b;
    }
}
__device__ __forceinline__ s16x8 zero8(){
    s16x8 z;
#pragma unroll
    for (int i = 0; i < 8; i++) z[i] = 0;
    return z;
}
__device__ __forceinline__ float sigm(float x){ return 1.f / (1.f + __expf(-x)); }
__device__ __forceinline__ float tanh_f(float x){ return 1.f - 2.f / (__expf(2.f * x) + 1.f); }

// ---- cross-WG: all shared data via relaxed sc1 atomics; h data carries its
// own readiness tag in bit30 of every packed word (self-synchronizing).
__device__ __forceinline__ void wait_ge(uint32_t* p, uint32_t v, uint32_t& seen){
    if (seen >= v) return;
    uint32_t c;
    while ((c = __hip_atomic_load(p, __ATOMIC_RELAXED, SC_AGENT)) < v)
        __builtin_amdgcn_s_sleep(1);
    seen = c;
    __asm__ volatile("" ::: "memory");
}
__device__ __forceinline__ void h_store(uint32_t* p, uint32_t v){
    __hip_atomic_store(p, v, __ATOMIC_RELAXED, SC_AGENT);
}
__device__ __forceinline__ void ld_raw4(const uint32_t* p, u64 w[4]){
#pragma unroll
    for (int i = 0; i < 4; i++)
        w[i] = __hip_atomic_load((const u64*)p + i, __ATOMIC_RELAXED, SC_AGENT);
}
__device__ __forceinline__ void unpack4(const u64 w[4], s16x8& ah, s16x8& al){
#pragma unroll
    for (int i = 0; i < 4; i++){
        u64 v = w[i] & STRIPM;
        uint32_t a = (uint32_t)v, b = (uint32_t)(v >> 32);
        ah[2*i]   = (short)(a >> 16); al[2*i]   = (short)(a & 0xffffu);
        ah[2*i+1] = (short)(b >> 16); al[2*i+1] = (short)(b & 0xffffu);
    }
}
__device__ __forceinline__ uint32_t tag_of(int t){ return (((uint32_t)t >> 2) & 1u) ^ 1u; }

__global__ void __launch_bounds__(256, 1)
lstm_fused(const float* __restrict__ x,
           const float* __restrict__ Wih0, const float* __restrict__ Whh0,
           const float* __restrict__ bih0, const float* __restrict__ bhh0,
           const float* __restrict__ Wih1, const float* __restrict__ Whh1,
           const float* __restrict__ bih1, const float* __restrict__ bhh1,
           const float* __restrict__ Wout, const float* __restrict__ bout,
           float* __restrict__ out, unsigned char* __restrict__ ws)
{
    extern __shared__ char smem[];
    float* part = (float*)smem;        // 2 x (8 slots * 256 f32) = 16 KB, dbuf by t&1

    const int tid  = threadIdx.x;
    const int wave = tid >> 6, lane = tid & 63;
    const int lm = lane & 15, lq = lane >> 4;
    const int mt = wave & 1, kh = wave >> 1;

    // XCD-cluster: all 16 WGs of a chunk share wg%8 (likely same XCD)
    const int wg = blockIdx.x;
    const int chunk = ((wg & 7) << 1) | ((wg >> 3) & 1);
    const int sub = wg >> 4;
    const int layer = sub >> 3, slice = sub & 7;
    const int b0 = chunk * CB;

    uint32_t* cnt1 = (uint32_t*)(ws + 4096 + chunk * 64);
    uint32_t* h0p  = (uint32_t*)(ws + 8192);                 // [NSLOT][512][128] packed hi|lo
    uint32_t* h1p  = h0p + (size_t)NSLOT * B_ALL * HID;

    uint32_t seen1 = 0;

    if (layer == 0){
        // ---- layer 0: gates = x @ Wih0^T + h0(t-1) @ Whh0^T ----
        s16x8 wh[4][3], wl[4][3];
#pragma unroll
        for (int g = 0; g < 4; g++)
#pragma unroll
            for (int ktl = 0; ktl < 3; ktl++){
                int kt = kh * 3 + ktl;
                int j = g * HID + slice * 16 + lm;
                const float* src = (kt < 2) ? (Wih0 + (size_t)j * SDIM + kt * 32 + lq * 8)
                                            : (Whh0 + (size_t)j * HID + (kt - 2) * 32 + lq * 8);
                load_split8(src, wh[g][ktl], wl[g][ktl]);
            }
        float bias[4];
#pragma unroll
        for (int g = 0; g < 4; g++){
            int j = g * HID + slice * 16 + lm;
            bias[g] = bih0[j] + bhh0[j];
        }
        float cst[4] = {0.f, 0.f, 0.f, 0.f};

        for (int t = 0; t < T_STEPS; t++){
            s16x8 Ah[3], Al[3];
            if (kh == 0){
                const float* xp = x + ((size_t)t * B_ALL + b0 + mt * 16 + lm) * SDIM;
#pragma unroll
                for (int kt = 0; kt < 2; kt++)
#pragma unroll
                    for (int j = 0; j < 8; j++){
                        unsigned short hh, ll; split_pair(xp[kt * 32 + lq * 8 + j], hh, ll);
                        Ah[kt][j] = (short)hh; Al[kt][j] = (short)ll;
                    }
            }
            if (t > 3) wait_ge(cnt1, PSTEP * (uint32_t)(t - 3), seen1);  // layer1 lag bound

            if (t > 0){
                const u64 want = tag_of(t - 1) ? TAGM : 0ull;
                const uint32_t* hr = h0p + ((size_t)((t - 1) & 3) * B_ALL + b0 + mt * 16 + lm) * HID;
                if (kh == 0){
                    u64 w0[4];
                    for (;;){
                        ld_raw4(hr + lq * 8, w0);
                        u64 bad = ((w0[0] & TAGM) ^ want) | ((w0[1] & TAGM) ^ want)
                                | ((w0[2] & TAGM) ^ want) | ((w0[3] & TAGM) ^ want);
                        if (!__any(bad != 0)) break;
                    }
                    unpack4(w0, Ah[2], Al[2]);
                } else {
                    u64 w[3][4];
                    for (;;){
#pragma unroll
                        for (int i = 0; i < 3; i++) ld_raw4(hr + 32 + i * 32 + lq * 8, w[i]);
                        u64 bad = 0;
#pragma unroll
                        for (int i = 0; i < 3; i++)
#pragma unroll
                            for (int j2 = 0; j2 < 4; j2++) bad |= ((w[i][j2] & TAGM) ^ want);
                        if (!__any(bad != 0)) break;
                    }
#pragma unroll
                    for (int i = 0; i < 3; i++) unpack4(w[i], Ah[i], Al[i]);
                }
            } else {
                if (kh == 0){ Ah[2] = zero8(); Al[2] = zero8(); }
                else {
#pragma unroll
                    for (int i = 0; i < 3; i++){ Ah[i] = zero8(); Al[i] = zero8(); }
                }
            }

            f32x4 acc[4];
#pragma unroll
            for (int g = 0; g < 4; g++) acc[g] = (f32x4){0.f, 0.f, 0.f, 0.f};
#pragma unroll
            for (int ktl = 0; ktl < 3; ktl++)
#pragma unroll
                for (int g = 0; g < 4; g++){
                    acc[g] = MFMA(Ah[ktl], wh[g][ktl], acc[g]);
                    acc[g] = MFMA(Ah[ktl], wl[g][ktl], acc[g]);
                    acc[g] = MFMA(Al[ktl], wh[g][ktl], acc[g]);
                }

            float* pb = part + ((t & 1) << 11);
            if (wave >= 2){
#pragma unroll
                for (int g = 0; g < 4; g++)
                    *(f32x4*)(pb + ((wave - 2) * 4 + g) * 256 + lane * 4) = acc[g];
            }
            __syncthreads();
            if (wave < 2){
#pragma unroll
                for (int g = 0; g < 4; g++)
                    acc[g] += *(f32x4*)(pb + (wave * 4 + g) * 256 + lane * 4);
                const uint32_t tagbits = tag_of(t) << 30;
                uint32_t* wrow = h0p + ((size_t)(t & 3) * B_ALL + b0 + mt * 16 + lq * 4) * HID
                               + slice * 16 + lm;
#pragma unroll
                for (int r = 0; r < 4; r++){
                    float zi = acc[0][r] + bias[0], zf = acc[1][r] + bias[1];
                    float zg = acc[2][r] + bias[2], zo = acc[3][r] + bias[3];
                    float cn = sigm(zf) * cst[r] + sigm(zi) * tanh_f(zg);
                    float hn = sigm(zo) * tanh_f(cn);
                    cst[r] = cn;
                    unsigned short hh, ll; split_h(hn, hh, ll);
                    h_store(wrow + (size_t)r * HID, (((uint32_t)hh << 16) | (uint32_t)ll) | tagbits);
                }
                // no drain, no signal: data carries its own tag
            }
        }
    } else {
        // ---- layer 1: gates = h0(t) @ Wih1^T + h1(t-1) @ Whh1^T; + action(t-1) ----
        s16x8 wh[4][4], wl[4][4];
#pragma unroll
        for (int g = 0; g < 4; g++)
#pragma unroll
            for (int ktl = 0; ktl < 4; ktl++){
                int kt = kh * 4 + ktl;
                int j = g * HID + slice * 16 + lm;
                const float* src = (kt < 4) ? (Wih1 + (size_t)j * HID + kt * 32 + lq * 8)
                                            : (Whh1 + (size_t)j * HID + (kt - 4) * 32 + lq * 8);
                load_split8(src, wh[g][ktl], wl[g][ktl]);
            }
        float bias[4];
#pragma unroll
        for (int g = 0; g < 4; g++){
            int j = g * HID + slice * 16 + lm;
            bias[g] = bih1[j] + bhh1[j];
        }
        float cst[4] = {0.f, 0.f, 0.f, 0.f};

        s16x8 oh[4], ol[4];
        float ob = 0.f;
#pragma unroll
        for (int ktl = 0; ktl < 4; ktl++)
#pragma unroll
            for (int i = 0; i < 8; i++){ oh[ktl][i] = 0; ol[ktl][i] = 0; }
        if (kh == 1 && lm < ADIM){
#pragma unroll
            for (int ktl = 0; ktl < 4; ktl++)
                load_split8(Wout + (size_t)lm * HID + ktl * 32 + lq * 8, oh[ktl], ol[ktl]);
            ob = bout[lm];
        }

        for (int t = 0; t < T_STEPS; t++){
            s16x8 Ah[4], Al[4];
            if (kh == 0){
                // h0(t), slot t&3, tag(t)
                const u64 want = tag_of(t) ? TAGM : 0ull;
                const uint32_t* hr = h0p + ((size_t)(t & 3) * B_ALL + b0 + mt * 16 + lm) * HID;
                u64 w[4][4];
                for (;;){
#pragma unroll
                    for (int i = 0; i < 4; i++) ld_raw4(hr + i * 32 + lq * 8, w[i]);
                    u64 bad = 0;
#pragma unroll
                    for (int i = 0; i < 4; i++)
#pragma unroll
                        for (int j2 = 0; j2 < 4; j2++) bad |= ((w[i][j2] & TAGM) ^ want);
                    if (!__any(bad != 0)) break;
                }
#pragma unroll
                for (int i = 0; i < 4; i++) unpack4(w[i], Ah[i], Al[i]);
            } else if (t > 0){
                // h1(t-1), slot (t-1)&3, tag(t-1)
                const u64 want = tag_of(t - 1) ? TAGM : 0ull;
                const uint32_t* hr = h1p + ((size_t)((t - 1) & 3) * B_ALL + b0 + mt * 16 + lm) * HID;
                u64 w[4][4];
                for (;;){
#pragma unroll
                    for (int i = 0; i < 4; i++) ld_raw4(hr + i * 32 + lq * 8, w[i]);
                    u64 bad = 0;
#pragma unroll
                    for (int i = 0; i < 4; i++)
#pragma unroll
                        for (int j2 = 0; j2 < 4; j2++) bad |= ((w[i][j2] & TAGM) ^ want);
                    if (!__any(bad != 0)) break;
                }
#pragma unroll
                for (int i = 0; i < 4; i++) unpack4(w[i], Ah[i], Al[i]);
            } else {
#pragma unroll
                for (int i = 0; i < 4; i++){ Ah[i] = zero8(); Al[i] = zero8(); }
            }

            f32x4 acc[4];
#pragma unroll
            for (int g = 0; g < 4; g++) acc[g] = (f32x4){0.f, 0.f, 0.f, 0.f};
#pragma unroll
            for (int ktl = 0; ktl < 4; ktl++)
#pragma unroll
                for (int g = 0; g < 4; g++){
                    acc[g] = MFMA(Ah[ktl], wh[g][ktl], acc[g]);
                    acc[g] = MFMA(Ah[ktl], wl[g][ktl], acc[g]);
                    acc[g] = MFMA(Al[ktl], wh[g][ktl], acc[g]);
                }

            float* pb = part + ((t & 1) << 11);
            if (wave >= 2){
#pragma unroll
                for (int g = 0; g < 4; g++)
                    *(f32x4*)(pb + ((wave - 2) * 4 + g) * 256 + lane * 4) = acc[g];
            }
            __syncthreads();
            if (wave < 2){
#pragma unroll
                for (int g = 0; g < 4; g++)
                    acc[g] += *(f32x4*)(pb + (wave * 4 + g) * 256 + lane * 4);
                const uint32_t tagbits = tag_of(t) << 30;
                uint32_t* wrow = h1p + ((size_t)(t & 3) * B_ALL + b0 + mt * 16 + lq * 4) * HID
                               + slice * 16 + lm;
#pragma unroll
                for (int r = 0; r < 4; r++){
                    float zi = acc[0][r] + bias[0], zf = acc[1][r] + bias[1];
                    float zg = acc[2][r] + bias[2], zo = acc[3][r] + bias[3];
                    float cn = sigm(zf) * cst[r] + sigm(zi) * tanh_f(zg);
                    float hn = sigm(zo) * tanh_f(cn);
                    cst[r] = cn;
                    unsigned short hh, ll; split_h(hn, hh, ll);
                    h_store(wrow + (size_t)r * HID, (((uint32_t)hh << 16) | (uint32_t)ll) | tagbits);
                }
                if (lane == 0)
                    __hip_atomic_fetch_add(cnt1, 1u, __ATOMIC_RELAXED, SC_AGENT);
            } else if (t > 0){
                // action(t-1) = tanh(h1(t-1) @ Wout^T + bout): reuse h1 frags in regs
                f32x4 oacc = (f32x4){0.f, 0.f, 0.f, 0.f};
#pragma unroll
                for (int ktl = 0; ktl < 4; ktl++){
                    oacc = MFMA(Ah[ktl], oh[ktl], oacc);
                    oacc = MFMA(Ah[ktl], ol[ktl], oacc);
                    oacc = MFMA(Al[ktl], oh[ktl], oacc);
                }
                if (lm < ADIM){
#pragma unroll
                    for (int r = 0; r < 4; r++){
                        int b = b0 + mt * 16 + lq * 4 + r;
                        out[((size_t)(t - 1) * B_ALL + b) * ADIM + lm] = tanh_f(oacc[r] + ob);
                    }
                }
            }
        }
        // epilogue: action(511) from h1(511) (slot 3, tag(511)=0)
        if (kh == 1){
            const u64 want = tag_of(T_STEPS - 1) ? TAGM : 0ull;
            const uint32_t* hr = h1p + ((size_t)3 * B_ALL + b0 + mt * 16 + lm) * HID;
            u64 w[4][4];
            for (;;){
#pragma unroll
                for (int i = 0; i < 4; i++) ld_raw4(hr + i * 32 + lq * 8, w[i]);
                u64 bad = 0;
#pragma unroll
                for (int i = 0; i < 4; i++)
#pragma unroll
                    for (int j2 = 0; j2 < 4; j2++) bad |= ((w[i][j2] & TAGM) ^ want);
                if (!__any(bad != 0)) break;
            }
            f32x4 oacc = (f32x4){0.f, 0.f, 0.f, 0.f};
#pragma unroll
            for (int ktl = 0; ktl < 4; ktl++){
                s16x8 Ah, Al;
                unpack4(w[ktl], Ah, Al);
                oacc = MFMA(Ah, oh[ktl], oacc);
                oacc = MFMA(Ah, ol[ktl], oacc);
                oacc = MFMA(Al, oh[ktl], oacc);
            }
            if (lm < ADIM){
#pragma unroll
                for (int r = 0; r < 4; r++){
                    int b = b0 + mt * 16 + lq * 4 + r;
                    out[((size_t)(T_STEPS - 1) * B_ALL + b) * ADIM + lm] = tanh_f(oacc[r] + ob);
                }
            }
        }
    }
}

extern "C" void kernel_launch(void* const* d_in, const int* in_sizes, int n_in,
                              void* d_out, int out_size, void* d_ws, size_t ws_size,
                              hipStream_t stream)
{
    (void)in_sizes; (void)n_in; (void)out_size; (void)ws_size;
    const float* x    = (const float*)d_in[0];
    const float* Wih0 = (const float*)d_in[1];
    const float* Whh0 = (const float*)d_in[2];
    const float* bih0 = (const float*)d_in[3];
    const float* bhh0 = (const float*)d_in[4];
    const float* Wih1 = (const float*)d_in[5];
    const float* Whh1 = (const float*)d_in[6];
    const float* bih1 = (const float*)d_in[7];
    const float* bhh1 = (const float*)d_in[8];
    const float* Wout = (const float*)d_in[9];
    const float* bout = (const float*)d_in[10];

    // ws: [4KB,5KB) cnt1 (16 x 64B), [8KB,...) h0/h1 packed(hi|lo) u32, NSLOT slots
    const size_t ws_used = 8192 + 2 * (size_t)NSLOT * B_ALL * HID * sizeof(uint32_t); // ~2.1 MB
    hipMemsetAsync(d_ws, 0, ws_used, stream);

    const size_t lds_bytes = 2 * 8 * 256 * sizeof(float);   // 16 KB dbuf partials
    hipLaunchKernelGGL(lstm_fused, dim3(256), dim3(256), lds_bytes, stream,
                       x, Wih0, Whh0, bih0, bhh0, Wih1, Whh1, bih1, bhh1, Wout, bout,
                       (float*)d_out, (unsigned char*)d_ws);
}

// Round 5
// 3432.570 us; speedup vs baseline: 1.0683x; 1.0683x over previous
//
#include <hip/hip_runtime.h>
#include <stdint.h>

#define T_STEPS 512
#define B_ALL   512
#define SDIM    64
#define HID     128
#define ADIM    10
#define CB      32      // batch rows per chunk
#define NS0     8       // h0 buffer depth
#define NS1     2       // h1 buffer depth (WG-barrier-proven safe)

typedef __attribute__((ext_vector_type(4))) float f32x4;
typedef __attribute__((ext_vector_type(8))) short s16x8;
typedef unsigned long long u64;

#define MFMA(a,b,c) __builtin_amdgcn_mfma_f32_16x16x32_bf16(a,b,c,0,0,0)
#define SC_AGENT __HIP_MEMORY_SCOPE_AGENT
#define M_ALL 0xFFFFFFFFFFFFFFFFull
#define M_S01 0x0303030303030303ull   // lanes with (lane&7)<2
#define M_S27 0xFCFCFCFCFCFCFCFCull   // lanes with (lane&7)>=2

__device__ __forceinline__ unsigned short bf_rne(float f){
    union{float f; unsigned int u;} v; v.f = f;
    unsigned int r = v.u + 0x7fffu + ((v.u >> 16) & 1u);
    return (unsigned short)(r >> 16);
}
__device__ __forceinline__ float us_to_f(unsigned short h){
    union{unsigned int u; float f;} v; v.u = ((unsigned int)h) << 16; return v.f;
}
__device__ __forceinline__ void split_pair(float f, unsigned short& hi, unsigned short& lo){
    hi = bf_rne(f);
    lo = bf_rne(f - us_to_f(hi));
}
__device__ __forceinline__ void load_split8(const float* p, s16x8& h, s16x8& l){
#pragma unroll
    for (int i = 0; i < 8; i++){
        unsigned short a, b; split_pair(p[i], a, b);
        h[i] = (short)a; l[i] = (short)b;
    }
}
__device__ __forceinline__ s16x8 zero8(){
    s16x8 z;
#pragma unroll
    for (int i = 0; i < 8; i++) z[i] = 0;
    return z;
}
__device__ __forceinline__ float sigm(float x){ return 1.f / (1.f + __expf(-x)); }
__device__ __forceinline__ float tanh_f(float x){ return 1.f - 2.f / (__expf(2.f * x) + 1.f); }

// ---- cross-WG: relaxed sc1 everywhere. Per-producer flag words (no RMW, no
// shared-line atomic convoy). Consumer: 1 flag load/lane + ballot per iter.
__device__ __forceinline__ void waitf(const uint32_t* f, int idx, uint32_t v, u64 M, uint32_t& seen){
    if (seen >= v) return;
    for (;;){
        uint32_t c = __hip_atomic_load(f + idx, __ATOMIC_RELAXED, SC_AGENT);
        u64 ok = __ballot(c >= v);
        if ((ok & M) == M) break;
        __builtin_amdgcn_s_sleep(1);
    }
    seen = v;
    __asm__ volatile("" ::: "memory");
}
__device__ __forceinline__ void flag_store(uint32_t* p, uint32_t v){
    __asm__ volatile("" ::: "memory");
    __builtin_amdgcn_s_waitcnt(0x0f70);   // vmcnt(0): h stores acked at coherence point
    __hip_atomic_store(p, v, __ATOMIC_RELAXED, SC_AGENT);
}
__device__ __forceinline__ void h_store(uint32_t* p, uint32_t v){
    __hip_atomic_store(p, v, __ATOMIC_RELAXED, SC_AGENT);
}
__device__ __forceinline__ void ld_raw4(const uint32_t* p, u64 w[4]){
#pragma unroll
    for (int i = 0; i < 4; i++)
        w[i] = __hip_atomic_load((const u64*)p + i, __ATOMIC_RELAXED, SC_AGENT);
}
__device__ __forceinline__ void unpack4(const u64 w[4], s16x8& ah, s16x8& al){
#pragma unroll
    for (int i = 0; i < 4; i++){
        uint32_t a = (uint32_t)w[i], b = (uint32_t)(w[i] >> 32);
        ah[2*i]   = (short)(a >> 16); al[2*i]   = (short)(a & 0xffffu);
        ah[2*i+1] = (short)(b >> 16); al[2*i+1] = (short)(b & 0xffffu);
    }
}

__global__ void __launch_bounds__(256, 1)
lstm_fused(const float* __restrict__ x,
           const float* __restrict__ Wih0, const float* __restrict__ Whh0,
           const float* __restrict__ bih0, const float* __restrict__ bhh0,
           const float* __restrict__ Wih1, const float* __restrict__ Whh1,
           const float* __restrict__ bih1, const float* __restrict__ bhh1,
           const float* __restrict__ Wout, const float* __restrict__ bout,
           float* __restrict__ out, unsigned char* __restrict__ ws)
{
    extern __shared__ char smem[];
    float* part = (float*)smem;        // 2 x (8 slots * 256 f32) = 16 KB, dbuf by t&1

    const int tid  = threadIdx.x;
    const int wave = tid >> 6, lane = tid & 63;
    const int lm = lane & 15, lq = lane >> 4;
    const int mt = wave & 1, kh = wave >> 1;

    // XCD-cluster: all 16 WGs of a chunk share wg&7 (same XCD under round-robin)
    const int wg = blockIdx.x;
    const int chunk = ((wg & 7) << 1) | ((wg >> 3) & 1);
    const int sub = wg >> 4;
    const int layer = sub >> 3, slice = sub & 7;
    const int b0 = chunk * CB;

    uint32_t* flags0 = (uint32_t*)(ws + chunk * 64);          // [mt][slice] u32
    uint32_t* flags1 = (uint32_t*)(ws + 4096 + chunk * 64);
    uint32_t* h0p = (uint32_t*)(ws + 8192);                   // [NS0][512][128] packed hi|lo
    uint32_t* h1p = h0p + (size_t)NS0 * B_ALL * HID;          // [NS1][512][128]

    uint32_t seen0 = 0, seen1 = 0;

    if (layer == 0){
        // ---- layer 0: gates = x @ Wih0^T + h0(t-1) @ Whh0^T ----
        s16x8 wh[4][3], wl[4][3];
#pragma unroll
        for (int g = 0; g < 4; g++)
#pragma unroll
            for (int ktl = 0; ktl < 3; ktl++){
                int kt = kh * 3 + ktl;
                int j = g * HID + slice * 16 + lm;
                const float* src = (kt < 2) ? (Wih0 + (size_t)j * SDIM + kt * 32 + lq * 8)
                                            : (Whh0 + (size_t)j * HID + (kt - 2) * 32 + lq * 8);
                load_split8(src, wh[g][ktl], wl[g][ktl]);
            }
        float bias[4];
#pragma unroll
        for (int g = 0; g < 4; g++){
            int j = g * HID + slice * 16 + lm;
            bias[g] = bih0[j] + bhh0[j];
        }
        float cst[4] = {0.f, 0.f, 0.f, 0.f};
        const u64 myM = (kh == 0) ? M_S01 : M_S27;   // h0 cols 0..31 vs 32..127

        for (int t = 0; t < T_STEPS; t++){
            s16x8 Ah[3], Al[3];
            if (kh == 0){
                const float* xp = x + ((size_t)t * B_ALL + b0 + mt * 16 + lm) * SDIM;
#pragma unroll
                for (int kt = 0; kt < 2; kt++)
#pragma unroll
                    for (int j = 0; j < 8; j++){
                        unsigned short hh, ll; split_pair(xp[kt * 32 + lq * 8 + j], hh, ll);
                        Ah[kt][j] = (short)hh; Al[kt][j] = (short)ll;
                    }
            }
            // lagged backpressure: writing slot t..t+3 kills h0(t-8..t-5);
            // layer1 read h0(t') at step t' -> need flags1 >= t-4 (checked /4 steps)
            if ((t & 3) == 0 && t >= 8)
                waitf(flags1, lane & 15, (uint32_t)(t - 4), M_ALL, seen1);
            if (t > 0)
                waitf(flags0, mt * 8 + (lane & 7), (uint32_t)t, myM, seen0);

            if (t > 0){
                const uint32_t* hr = h0p + ((size_t)((t - 1) & 7) * B_ALL + b0 + mt * 16 + lm) * HID;
                if (kh == 0){
                    u64 w0[4];
                    ld_raw4(hr + lq * 8, w0);
                    unpack4(w0, Ah[2], Al[2]);
                } else {
                    u64 w[3][4];
#pragma unroll
                    for (int i = 0; i < 3; i++) ld_raw4(hr + 32 + i * 32 + lq * 8, w[i]);
#pragma unroll
                    for (int i = 0; i < 3; i++) unpack4(w[i], Ah[i], Al[i]);
                }
            } else {
                if (kh == 0){ Ah[2] = zero8(); Al[2] = zero8(); }
                else {
#pragma unroll
                    for (int i = 0; i < 3; i++){ Ah[i] = zero8(); Al[i] = zero8(); }
                }
            }

            f32x4 acc[4];
#pragma unroll
            for (int g = 0; g < 4; g++) acc[g] = (f32x4){0.f, 0.f, 0.f, 0.f};
#pragma unroll
            for (int ktl = 0; ktl < 3; ktl++)
#pragma unroll
                for (int g = 0; g < 4; g++){
                    acc[g] = MFMA(Ah[ktl], wh[g][ktl], acc[g]);
                    acc[g] = MFMA(Ah[ktl], wl[g][ktl], acc[g]);
                    acc[g] = MFMA(Al[ktl], wh[g][ktl], acc[g]);
                }

            float* pb = part + ((t & 1) << 11);
            if (wave >= 2){
#pragma unroll
                for (int g = 0; g < 4; g++)
                    *(f32x4*)(pb + ((wave - 2) * 4 + g) * 256 + lane * 4) = acc[g];
            }
            __syncthreads();
            if (wave < 2){
#pragma unroll
                for (int g = 0; g < 4; g++)
                    acc[g] += *(f32x4*)(pb + (wave * 4 + g) * 256 + lane * 4);
                uint32_t* wrow = h0p + ((size_t)(t & 7) * B_ALL + b0 + mt * 16 + lq * 4) * HID
                               + slice * 16 + lm;
#pragma unroll
                for (int r = 0; r < 4; r++){
                    float zi = acc[0][r] + bias[0], zf = acc[1][r] + bias[1];
                    float zg = acc[2][r] + bias[2], zo = acc[3][r] + bias[3];
                    float cn = sigm(zf) * cst[r] + sigm(zi) * tanh_f(zg);
                    float hn = sigm(zo) * tanh_f(cn);
                    cst[r] = cn;
                    unsigned short hh, ll; split_pair(hn, hh, ll);
                    h_store(wrow + (size_t)r * HID, ((uint32_t)hh << 16) | (uint32_t)ll);
                }
                if (lane == 0) flag_store(flags0 + mt * 8 + slice, (uint32_t)(t + 1));
            }
        }
    } else {
        // ---- layer 1: gates = h0(t) @ Wih1^T + h1(t-1) @ Whh1^T; + action(t-1) ----
        s16x8 wh[4][4], wl[4][4];
#pragma unroll
        for (int g = 0; g < 4; g++)
#pragma unroll
            for (int ktl = 0; ktl < 4; ktl++){
                int kt = kh * 4 + ktl;
                int j = g * HID + slice * 16 + lm;
                const float* src = (kt < 4) ? (Wih1 + (size_t)j * HID + kt * 32 + lq * 8)
                                            : (Whh1 + (size_t)j * HID + (kt - 4) * 32 + lq * 8);
                load_split8(src, wh[g][ktl], wl[g][ktl]);
            }
        float bias[4];
#pragma unroll
        for (int g = 0; g < 4; g++){
            int j = g * HID + slice * 16 + lm;
            bias[g] = bih1[j] + bhh1[j];
        }
        float cst[4] = {0.f, 0.f, 0.f, 0.f};

        s16x8 oh[4], ol[4];
        float ob = 0.f;
#pragma unroll
        for (int ktl = 0; ktl < 4; ktl++)
#pragma unroll
            for (int i = 0; i < 8; i++){ oh[ktl][i] = 0; ol[ktl][i] = 0; }
        if (kh == 1 && lm < ADIM){
#pragma unroll
            for (int ktl = 0; ktl < 4; ktl++)
                load_split8(Wout + (size_t)lm * HID + ktl * 32 + lq * 8, oh[ktl], ol[ktl]);
            ob = bout[lm];
        }

        for (int t = 0; t < T_STEPS; t++){
            s16x8 Ah[4], Al[4];
            if (kh == 0){
                waitf(flags0, mt * 8 + (lane & 7), (uint32_t)(t + 1), M_ALL, seen0);  // h0(t)
                const uint32_t* hr = h0p + ((size_t)(t & 7) * B_ALL + b0 + mt * 16 + lm) * HID;
                u64 w[4][4];
#pragma unroll
                for (int i = 0; i < 4; i++) ld_raw4(hr + i * 32 + lq * 8, w[i]);
#pragma unroll
                for (int i = 0; i < 4; i++) unpack4(w[i], Ah[i], Al[i]);
            } else if (t > 0){
                waitf(flags1, mt * 8 + (lane & 7), (uint32_t)t, M_ALL, seen1);        // h1(t-1)
                const uint32_t* hr = h1p + ((size_t)((t - 1) & 1) * B_ALL + b0 + mt * 16 + lm) * HID;
                u64 w[4][4];
#pragma unroll
                for (int i = 0; i < 4; i++) ld_raw4(hr + i * 32 + lq * 8, w[i]);
#pragma unroll
                for (int i = 0; i < 4; i++) unpack4(w[i], Ah[i], Al[i]);
            } else {
#pragma unroll
                for (int i = 0; i < 4; i++){ Ah[i] = zero8(); Al[i] = zero8(); }
            }

            f32x4 acc[4];
#pragma unroll
            for (int g = 0; g < 4; g++) acc[g] = (f32x4){0.f, 0.f, 0.f, 0.f};
#pragma unroll
            for (int ktl = 0; ktl < 4; ktl++)
#pragma unroll
                for (int g = 0; g < 4; g++){
                    acc[g] = MFMA(Ah[ktl], wh[g][ktl], acc[g]);
                    acc[g] = MFMA(Ah[ktl], wl[g][ktl], acc[g]);
                    acc[g] = MFMA(Al[ktl], wh[g][ktl], acc[g]);
                }

            float* pb = part + ((t & 1) << 11);
            if (wave >= 2){
#pragma unroll
                for (int g = 0; g < 4; g++)
                    *(f32x4*)(pb + ((wave - 2) * 4 + g) * 256 + lane * 4) = acc[g];
            }
            __syncthreads();
            if (wave < 2){
#pragma unroll
                for (int g = 0; g < 4; g++)
                    acc[g] += *(f32x4*)(pb + (wave * 4 + g) * 256 + lane * 4);
                uint32_t* wrow = h1p + ((size_t)(t & 1) * B_ALL + b0 + mt * 16 + lq * 4) * HID
                               + slice * 16 + lm;
#pragma unroll
                for (int r = 0; r < 4; r++){
                    float zi = acc[0][r] + bias[0], zf = acc[1][r] + bias[1];
                    float zg = acc[2][r] + bias[2], zo = acc[3][r] + bias[3];
                    float cn = sigm(zf) * cst[r] + sigm(zi) * tanh_f(zg);
                    float hn = sigm(zo) * tanh_f(cn);
                    cst[r] = cn;
                    unsigned short hh, ll; split_pair(hn, hh, ll);
                    h_store(wrow + (size_t)r * HID, ((uint32_t)hh << 16) | (uint32_t)ll);
                }
                if (lane == 0) flag_store(flags1 + mt * 8 + slice, (uint32_t)(t + 1));
            } else if (t > 0){
                // action(t-1) = tanh(h1(t-1) @ Wout^T + bout): reuse h1 frags in regs
                f32x4 oacc = (f32x4){0.f, 0.f, 0.f, 0.f};
#pragma unroll
                for (int ktl = 0; ktl < 4; ktl++){
                    oacc = MFMA(Ah[ktl], oh[ktl], oacc);
                    oacc = MFMA(Ah[ktl], ol[ktl], oacc);
                    oacc = MFMA(Al[ktl], oh[ktl], oacc);
                }
                if (lm < ADIM){
#pragma unroll
                    for (int r = 0; r < 4; r++){
                        int b = b0 + mt * 16 + lq * 4 + r;
                        out[((size_t)(t - 1) * B_ALL + b) * ADIM + lm] = tanh_f(oacc[r] + ob);
                    }
                }
            }
        }
        // epilogue: action(511) from h1(511) (slot 511&1 = 1)
        if (kh == 1){
            waitf(flags1, mt * 8 + (lane & 7), (uint32_t)T_STEPS, M_ALL, seen1);
            const uint32_t* hr = h1p + ((size_t)1 * B_ALL + b0 + mt * 16 + lm) * HID;
            f32x4 oacc = (f32x4){0.f, 0.f, 0.f, 0.f};
#pragma unroll
            for (int ktl = 0; ktl < 4; ktl++){
                u64 w[4]; s16x8 Ah, Al;
                ld_raw4(hr + ktl * 32 + lq * 8, w);
                unpack4(w, Ah, Al);
                oacc = MFMA(Ah, oh[ktl], oacc);
                oacc = MFMA(Ah, ol[ktl], oacc);
                oacc = MFMA(Al, oh[ktl], oacc);
            }
            if (lm < ADIM){
#pragma unroll
                for (int r = 0; r < 4; r++){
                    int b = b0 + mt * 16 + lq * 4 + r;
                    out[((size_t)(T_STEPS - 1) * B_ALL + b) * ADIM + lm] = tanh_f(oacc[r] + ob);
                }
            }
        }
    }
}

extern "C" void kernel_launch(void* const* d_in, const int* in_sizes, int n_in,
                              void* d_out, int out_size, void* d_ws, size_t ws_size,
                              hipStream_t stream)
{
    (void)in_sizes; (void)n_in; (void)out_size; (void)ws_size;
    const float* x    = (const float*)d_in[0];
    const float* Wih0 = (const float*)d_in[1];
    const float* Whh0 = (const float*)d_in[2];
    const float* bih0 = (const float*)d_in[3];
    const float* bhh0 = (const float*)d_in[4];
    const float* Wih1 = (const float*)d_in[5];
    const float* Whh1 = (const float*)d_in[6];
    const float* bih1 = (const float*)d_in[7];
    const float* bhh1 = (const float*)d_in[8];
    const float* Wout = (const float*)d_in[9];
    const float* bout = (const float*)d_in[10];

    // ws: [0,1KB) flags0, [4KB,5KB) flags1 (16 chunks x 64B each),
    //     [8KB,...) h0 [NS0 slots] + h1 [NS1 slots], packed(hi|lo) u32
    hipMemsetAsync(d_ws, 0, 8192, stream);   // flags only; h planes written before read

    const size_t lds_bytes = 2 * 8 * 256 * sizeof(float);   // 16 KB dbuf partials
    hipLaunchKernelGGL(lstm_fused, dim3(256), dim3(256), lds_bytes, stream,
                       x, Wih0, Whh0, bih0, bhh0, Wih1, Whh1, bih1, bhh1, Wout, bout,
                       (float*)d_out, (unsigned char*)d_ws);
}